// Round 16
// baseline (167.734 us; speedup 1.0000x reference)
//
#include <hip/hip_runtime.h>
#include <math.h>

#define Bn 4
#define Cn 32
#define Dn 64
#define Hn 64
#define Wn 64
#define HW (Hn * Wn)
#define DHW (Dn * Hn * Wn)      /* 262144 */
#define TOT (Bn * Cn * DHW)     /* 33554432 */
#define NCHUNK 128              /* spatial chunks per batch in reduce */
#define NW1 2744                /* 4*2*7*7*7 */

typedef float f4 __attribute__((ext_vector_type(4)));

// ============================================================
// Kernel 0: one-time weight reorder into workspace:
//   w1r[((ic*7+kh)*7+kw)*28 + kd*4 + oc] = w1[oc][ic][kd][kh][kw]
// -> per (ic,kh,kw) the 28 weights are contiguous: 7 s_load_dwordx4.
// ============================================================
__global__ __launch_bounds__(256) void wreorder_kernel(
    const float* __restrict__ w1, float* __restrict__ w1r) {
    const int i = blockIdx.x * 256 + threadIdx.x;
    if (i < NW1) {
        const int g = i / 28, r = i - g * 28;
        const int kd = r >> 2, oc = r & 3;
        const int ic = g / 49;
        const int kh = (g / 7) % 7;
        const int kw = g % 7;
        w1r[i] = w1[(((oc * 2 + ic) * 7 + kd) * 7 + kh) * 7 + kw];
    }
}

// ============================================================
// Kernel 1: fused reductions — R9/R15-measured variant (~30 us).
// ============================================================
__global__ __launch_bounds__(256) void reduce_kernel(
    const float* __restrict__ x,
    float* __restrict__ s_avg, float* __restrict__ s_max,
    float* __restrict__ part_sum, float* __restrict__ part_max) {
    const int b = blockIdx.x / NCHUNK;
    const int chunk = blockIdx.x % NCHUNK;
    const int base = chunk * 2048 + threadIdx.x * 4;
    const int lane = threadIdx.x & 63;
    const int wid = threadIdx.x >> 6;

    f4 ssum0 = {0.f, 0.f, 0.f, 0.f}, ssum1 = {0.f, 0.f, 0.f, 0.f};
    f4 smax0 = {-INFINITY, -INFINITY, -INFINITY, -INFINITY};
    f4 smax1 = smax0;
    float tsum[Cn], tmax[Cn];

    const float* xp = x + (size_t)b * Cn * DHW + base;
#pragma unroll
    for (int c = 0; c < Cn; ++c) {
        const f4 v0 = *reinterpret_cast<const f4*>(xp + (size_t)c * DHW);
        const f4 v1 = *reinterpret_cast<const f4*>(xp + (size_t)c * DHW + 1024);
        ssum0 += v0; ssum1 += v1;
        smax0.x = fmaxf(smax0.x, v0.x); smax0.y = fmaxf(smax0.y, v0.y);
        smax0.z = fmaxf(smax0.z, v0.z); smax0.w = fmaxf(smax0.w, v0.w);
        smax1.x = fmaxf(smax1.x, v1.x); smax1.y = fmaxf(smax1.y, v1.y);
        smax1.z = fmaxf(smax1.z, v1.z); smax1.w = fmaxf(smax1.w, v1.w);
        const float s0 = (v0.x + v0.y) + (v0.z + v0.w);
        const float s1 = (v1.x + v1.y) + (v1.z + v1.w);
        tsum[c] = s0 + s1;
        const float m0 = fmaxf(fmaxf(v0.x, v0.y), fmaxf(v0.z, v0.w));
        const float m1 = fmaxf(fmaxf(v1.x, v1.y), fmaxf(v1.z, v1.w));
        tmax[c] = fmaxf(m0, m1);
    }

    float* avp = s_avg + (size_t)b * DHW + base;
    float* mxp = s_max + (size_t)b * DHW + base;
    *reinterpret_cast<f4*>(avp) = ssum0 * (1.f / Cn);
    *reinterpret_cast<f4*>(avp + 1024) = ssum1 * (1.f / Cn);
    *reinterpret_cast<f4*>(mxp) = smax0;
    *reinterpret_cast<f4*>(mxp + 1024) = smax1;

    __shared__ float redS[4][Cn];
    __shared__ float redM[4][Cn];
#pragma unroll
    for (int c = 0; c < Cn; ++c) {
        float ps = tsum[c], pm = tmax[c];
#pragma unroll
        for (int off = 32; off; off >>= 1) {
            ps += __shfl_xor(ps, off);
            pm = fmaxf(pm, __shfl_xor(pm, off));
        }
        if (lane == 0) { redS[wid][c] = ps; redM[wid][c] = pm; }
    }
    __syncthreads();
    if (threadIdx.x < Cn) {
        const int c = threadIdx.x;
        float s = (redS[0][c] + redS[1][c]) + (redS[2][c] + redS[3][c]);
        float m = fmaxf(fmaxf(redM[0][c], redM[1][c]),
                        fmaxf(redM[2][c], redM[3][c]));
        part_sum[(b * Cn + c) * NCHUNK + chunk] = s;
        part_max[(b * Cn + c) * NCHUNK + chunk] = m;
    }
}

// ============================================================
// Kernel 2: partial-reduce + channel-attention MLP. 1 block, 256 threads.
// ============================================================
__global__ __launch_bounds__(256) void ca_kernel(
    const float* __restrict__ part_sum, const float* __restrict__ part_max,
    const float* __restrict__ fc1_w, const float* __restrict__ fc1_b,
    const float* __restrict__ fc2_w, const float* __restrict__ fc2_b,
    float* __restrict__ ca) {
    __shared__ float inpAll[Bn][64];
    __shared__ float h[128];
    const int t = threadIdx.x;
    {
        const int which = t >> 7;        // 0: sum, 1: max
        const int b = (t >> 5) & 3;
        const int c = t & 31;
        const f4* p4 = reinterpret_cast<const f4*>(
            (which ? part_max : part_sum) + (b * Cn + c) * NCHUNK);
        if (which == 0) {
            float acc = 0.f;
#pragma unroll
            for (int i = 0; i < NCHUNK / 4; ++i) {
                f4 v = p4[i];
                acc += (v.x + v.y) + (v.z + v.w);
            }
            inpAll[b][c] = acc * (1.f / DHW);
        } else {
            float m = -INFINITY;
#pragma unroll
            for (int i = 0; i < NCHUNK / 4; ++i) {
                f4 v = p4[i];
                m = fmaxf(m, fmaxf(fmaxf(v.x, v.y), fmaxf(v.z, v.w)));
            }
            inpAll[b][Cn + c] = m;
        }
    }
    __syncthreads();
#pragma unroll 1
    for (int b = 0; b < Bn; ++b) {
        if (t < 128) {
            float acc = fc1_b[t];
#pragma unroll
            for (int k = 0; k < 64; ++k) acc += fc1_w[t * 64 + k] * inpAll[b][k];
            h[t] = fmaxf(acc, 0.f);
        }
        __syncthreads();
        if (t < Cn) {
            float a2 = fc2_b[t];
#pragma unroll
            for (int k = 0; k < 128; ++k) a2 += fc2_w[t * 128 + k] * h[k];
            ca[b * Cn + t] = 1.f / (1.f + expf(-a2));
        }
        __syncthreads();
    }
}

// ============================================================
// Kernel 3: conv + epilogue (R15 structure) with software-pipelinable
// inner loop: kw FULLY UNROLLED + contiguous-weight s_load_dwordx4.
//  R15 diagnosis: per-(kh,kw) {10 ds_read + 28 scattered s_load ->
//  lgkmcnt(0) -> 112 FMA} exposes ~250cyc/iter (VALUBusy 47%). With kw
//  unrolled the scheduler hoists next-iter loads above current FMAs and
//  emits counted lgkmcnt(N) waits.
// ============================================================
#define TZc 4
#define TYc 4
#define LXc (Wn + 6)   /* 70 */
#define LYc (TYc + 6)  /* 10 */
#define LZc (TZc + 6)  /* 10 */
#define HALO1 (LZc * LYc * LXc)  /* 7000 floats = 28 KB */

__global__ __launch_bounds__(256) void conv_kernel(
    const float* __restrict__ ca_g,
    const float* __restrict__ s_avg, const float* __restrict__ s_max,
    const float* __restrict__ w1r, const float* __restrict__ w2,
    float* __restrict__ out) {
    __shared__ float sIn[HALO1];              // 28 KB (reused per ic)
    __shared__ float sv_s[TZc * TYc * Wn];    // 4 KB
    __shared__ float ca_s[Cn];

    const int t = threadIdx.x;
    const int bid = blockIdx.x;
    const int b = bid >> 8;            // 256 tiles per batch
    const int tile = bid & 255;
    const int tz = tile >> 4, ty = tile & 15;
    const int z0 = tz * TZc, y0 = ty * TYc;

    if (t < Cn) ca_s[t] = ca_g[b * Cn + t];

    const float* srcA = s_avg + (size_t)b * DHW;
    const float* srcM = s_max + (size_t)b * DHW;

    const int lx = t & 63, ly = t >> 6;

    float a0[TZc] = {0.f, 0.f, 0.f, 0.f};
    float a1[TZc] = {0.f, 0.f, 0.f, 0.f};
    float a2[TZc] = {0.f, 0.f, 0.f, 0.f};
    float a3[TZc] = {0.f, 0.f, 0.f, 0.f};

#pragma unroll 1
    for (int ic = 0; ic < 2; ++ic) {
        __syncthreads();  // protect sIn reuse (iter 0: orders ca_s too)
        const float* src = ic ? srcM : srcA;
        for (int i = t; i < HALO1; i += 256) {
            const int xx = i % LXc;
            const int rem = i / LXc;
            const int yy = rem % LYc;
            const int zz = rem / LYc;
            const int gz = z0 + zz - 3, gy = y0 + yy - 3, gx = xx - 3;
            float v = 0.f;
            if ((unsigned)gz < (unsigned)Dn && (unsigned)gy < (unsigned)Hn &&
                (unsigned)gx < (unsigned)Wn)
                v = src[(gz * Hn + gy) * Wn + gx];
            sIn[i] = v;
        }
        __syncthreads();

#pragma unroll 1
        for (int kh = 0; kh < 7; ++kh) {
            const int rowb = (ly + kh) * LXc + lx;
            const f4* wgh = reinterpret_cast<const f4*>(
                w1r + ((ic * 7 + kh) * 7) * 28);
#pragma unroll
            for (int kw = 0; kw < 7; ++kw) {
                float incol[LZc];
#pragma unroll
                for (int s = 0; s < LZc; ++s)
                    incol[s] = sIn[rowb + kw + s * (LYc * LXc)];
                const f4* wg = wgh + kw * 7;   // wave-uniform -> s_load_x4
#pragma unroll
                for (int kd = 0; kd < 7; ++kd) {
                    const f4 wv = wg[kd];
#pragma unroll
                    for (int o = 0; o < TZc; ++o) {
                        const float iv = incol[o + kd];
                        a0[o] += iv * wv.x;
                        a1[o] += iv * wv.y;
                        a2[o] += iv * wv.z;
                        a3[o] += iv * wv.w;
                    }
                }
            }
        }
    }

    const float c20 = w2[0], c21 = w2[1], c22 = w2[2], c23 = w2[3];
#pragma unroll
    for (int o = 0; o < TZc; ++o) {
        float s = fmaxf(a0[o], 0.f) * c20 + fmaxf(a1[o], 0.f) * c21 +
                  fmaxf(a2[o], 0.f) * c22 + fmaxf(a3[o], 0.f) * c23;
        sv_s[(o * TYc + ly) * Wn + lx] = 1.f / (1.f + expf(-s));
    }
    __syncthreads();

    // ---- epilogue: per combo a wave writes 1KB contiguous per stream ----
    const int wv = t >> 6, ln = t & 63;
    const f4* sv4 = reinterpret_cast<const f4*>(sv_s);
    f4* out4 = reinterpret_cast<f4*>(out);
    const size_t totq4 = TOT / 4;
#pragma unroll 1
    for (int combo = wv; combo < Cn * TZc; combo += 4) {
        const int c = combo >> 2, oz = combo & 3;
        const float cav = ca_s[c];
        const f4 v = sv4[oz * 64 + ln];
        const f4 att = v * cav;
        const f4 anti = 1.f - att;
        const size_t off = (((size_t)(b * Cn + c) * DHW) >> 2) +
                           (size_t)(z0 + oz) * (HW / 4) +
                           (size_t)y0 * (Wn / 4) + ln;
        __builtin_nontemporal_store(att, &out4[off]);
        __builtin_nontemporal_store(anti, &out4[totq4 + off]);
    }
}

extern "C" void kernel_launch(void* const* d_in, const int* in_sizes, int n_in,
                              void* d_out, int out_size, void* d_ws,
                              size_t ws_size, hipStream_t stream) {
    const float* x = (const float*)d_in[0];
    const float* fc1_w = (const float*)d_in[1];
    const float* fc1_b = (const float*)d_in[2];
    const float* fc2_w = (const float*)d_in[3];
    const float* fc2_b = (const float*)d_in[4];
    const float* conv1_w = (const float*)d_in[5];
    const float* conv2_w = (const float*)d_in[6];

    float* ws = (float*)d_ws;
    float* s_avg = ws;                               // B*DHW
    float* s_max = s_avg + (size_t)Bn * DHW;         // B*DHW
    float* part_sum = s_max + (size_t)Bn * DHW;      // B*C*NCHUNK
    float* part_max = part_sum + Bn * Cn * NCHUNK;   // B*C*NCHUNK
    float* ca = part_max + Bn * Cn * NCHUNK;         // B*C
    float* w1r = ca + Bn * Cn;                       // NW1

    wreorder_kernel<<<(NW1 + 255) / 256, 256, 0, stream>>>(conv1_w, w1r);
    reduce_kernel<<<Bn * NCHUNK, 256, 0, stream>>>(x, s_avg, s_max, part_sum,
                                                   part_max);
    ca_kernel<<<1, 256, 0, stream>>>(part_sum, part_max, fc1_w, fc1_b, fc2_w,
                                     fc2_b, ca);
    conv_kernel<<<Bn * 256, 256, 0, stream>>>(ca, s_avg, s_max, w1r, conv2_w,
                                              (float*)d_out);
}